// Round 12
// baseline (54.922 us; speedup 1.0000x reference)
//
#include <hip/hip_runtime.h>
#include <math.h>

// One 256-thread block per walker. S=2, N=8, D=256, I=4.
// Zero-hs design: dot reads h DIRECTLY from global (coalesced float4 rows);
// dist computed per-lane from r (no dist_s); store re-reads h (L2-hot) and
// writes NONTEMPORAL. LDS = Ms + anti only (1.3 KB). 2 barriers, not 3.

typedef float f32x4 __attribute__((ext_vector_type(4)));

__global__ __launch_bounds__(256, 8)
void orbital_cof_kernel(const float* __restrict__ h_g,   // (B,16,256)
                        const float* __restrict__ r_g,   // (B,16,4,3)
                        const float* __restrict__ W_g,   // (2,256,8)
                        const float* __restrict__ b_g,   // (2,8)
                        const float* __restrict__ dec_g, // (2,4,8)
                        const float* __restrict__ pi_g,  // (2,4,8)
                        float* __restrict__ out,         // (2,B,8,256)
                        int nb)
{
    __shared__ float Ms[2][8][8];
    __shared__ float anti_s[16];

    const int t = threadIdx.x;
    const int b = blockIdx.x;
    const int wave = t >> 6;         // 0..3
    const int lane = t & 63;
    const int s  = wave >> 1;        // spin
    const int kh = wave & 1;         // k half

    // ---- W into registers: lane covers d0=4*lane..+4, k=kh*4..+4 ----
    float wv[4][4];
    {
        const float* wp = W_g + s * 2048 + lane * 32 + kh * 4;
#pragma unroll
        for (int dd = 0; dd < 4; ++dd) {
            float4 w = *(const float4*)(wp + dd * 8);
            wv[dd][0] = w.x; wv[dd][1] = w.y; wv[dd][2] = w.z; wv[dd][3] = w.w;
        }
    }

    // ---- dot: read h rows straight from global (coalesced float4 per row) ----
    const float* hb = h_g + (size_t)b * 4096 + s * 2048 + lane * 4;
    float v[32];
#pragma unroll
    for (int n = 0; n < 8; ++n) {
        float4 hv = *(const float4*)(hb + n * 256);
#pragma unroll
        for (int kl = 0; kl < 4; ++kl) {
            float acc;
            acc = hv.x * wv[0][kl];
            acc = fmaf(hv.y, wv[1][kl], acc);
            acc = fmaf(hv.z, wv[2][kl], acc);
            acc = fmaf(hv.w, wv[3][kl], acc);
            v[n * 4 + kl] = acc;
        }
    }

    // ---- halving-butterfly reduce over 64 lanes (lane 2m -> entry m) ----
#pragma unroll
    for (int i = 0; i < 16; ++i) {
        float send = (lane & 32) ? v[i] : v[i + 16];
        float recv = __shfl_xor(send, 32);
        v[i] = ((lane & 32) ? v[i + 16] : v[i]) + recv;
    }
#pragma unroll
    for (int i = 0; i < 8; ++i) {
        float send = (lane & 16) ? v[i] : v[i + 8];
        float recv = __shfl_xor(send, 16);
        v[i] = ((lane & 16) ? v[i + 8] : v[i]) + recv;
    }
#pragma unroll
    for (int i = 0; i < 4; ++i) {
        float send = (lane & 8) ? v[i] : v[i + 4];
        float recv = __shfl_xor(send, 8);
        v[i] = ((lane & 8) ? v[i + 4] : v[i]) + recv;
    }
#pragma unroll
    for (int i = 0; i < 2; ++i) {
        float send = (lane & 4) ? v[i] : v[i + 2];
        float recv = __shfl_xor(send, 4);
        v[i] = ((lane & 4) ? v[i + 2] : v[i]) + recv;
    }
    {
        float send = (lane & 2) ? v[0] : v[1];
        float recv = __shfl_xor(send, 2);
        v[0] = ((lane & 2) ? v[1] : v[0]) + recv;
    }
    float tot = v[0] + __shfl_xor(v[0], 1);

    // ---- env + bias: every lane computes its pair-entry (idx = lane>>1);
    //      dist from r directly (12 tiny L1/L2-hot loads, 4 sqrt) ----
    {
        int idx = lane >> 1;         // n*4 + kl
        int nm = idx >> 2;
        int k = kh * 4 + (idx & 3);
        const float* rp = r_g + (size_t)b * 192 + (s * 32 + nm * 4) * 3;
        float env = 0.f;
#pragma unroll
        for (int i = 0; i < 4; ++i) {
            float x = rp[i * 3], y = rp[i * 3 + 1], z = rp[i * 3 + 2];
            float dd = sqrtf(x * x + y * y + z * z);
            env = fmaf(pi_g[s * 32 + i * 8 + k], __expf(-dd * dec_g[s * 32 + i * 8 + k]), env);
        }
        float m = (tot + b_g[s * 8 + k]) * env;
        if ((lane & 1) == 0) Ms[s][nm][k] = m;
    }
    __syncthreads();

    // ---- 16 cofactor determinants (7x7, partial pivoting) ----
    if (t < 16) {
        int ss = t >> 3;
        int n = t & 7;
        float a[7][7];
#pragma unroll
        for (int i = 0; i < 7; ++i) {
            int src = i + (i >= n);  // skip row n
#pragma unroll
            for (int j = 0; j < 7; ++j) a[i][j] = Ms[ss][src][j + 1];  // skip col 0
        }
        float det = 1.f;
#pragma unroll
        for (int kk = 0; kk < 7; ++kk) {
#pragma unroll
            for (int i = kk + 1; i < 7; ++i) {
                bool sw = fabsf(a[i][kk]) > fabsf(a[kk][kk]);
#pragma unroll
                for (int j = kk; j < 7; ++j) {
                    float tk = a[kk][j], ti = a[i][j];
                    a[kk][j] = sw ? ti : tk;
                    a[i][j]  = sw ? tk : ti;
                }
                det = sw ? -det : det;
            }
            float piv = a[kk][kk];
            det *= piv;
            float rp2 = (piv != 0.f) ? (1.f / piv) : 0.f;
#pragma unroll
            for (int i = kk + 1; i < 7; ++i) {
                float f = a[i][kk] * rp2;
#pragma unroll
                for (int j = kk + 1; j < 7; ++j) a[i][j] = fmaf(-f, a[kk][j], a[i][j]);
            }
        }
        float sgn = (n & 1) ? -1.f : 1.f;
        anti_s[t] = Ms[ss][n][0] * sgn * det;
    }
    __syncthreads();

    // ---- store: re-read h from global (L2-hot), scale, NT store ----
    const float4* h4p = (const float4*)(h_g + (size_t)b * 4096);
#pragma unroll
    for (int it = 0; it < 4; ++it) {
        int f4 = t + it * 256;
        int row = f4 >> 6;           // s*8+n
        int d4 = (f4 & 63) << 2;
        float4 hv = h4p[f4];
        float aa = anti_s[row];
        f32x4 o;
        o.x = hv.x * aa; o.y = hv.y * aa; o.z = hv.z * aa; o.w = hv.w * aa;
        int so = row >> 3;
        int n = row & 7;
        size_t off = (size_t)so * (size_t)nb * 2048 + (size_t)b * 2048 + (size_t)(n * 256 + d4);
        __builtin_nontemporal_store(o, (f32x4*)(out + off));
    }
}

extern "C" void kernel_launch(void* const* d_in, const int* in_sizes, int n_in,
                              void* d_out, int out_size, void* d_ws, size_t ws_size,
                              hipStream_t stream) {
    int nb = in_sizes[0] / 4096;     // B = elems / (S*N*D)
    const float* h_g   = (const float*)d_in[0];
    const float* r_g   = (const float*)d_in[1];
    const float* W_g   = (const float*)d_in[2];
    const float* b_g   = (const float*)d_in[3];
    const float* dec_g = (const float*)d_in[4];
    const float* pi_g  = (const float*)d_in[5];
    orbital_cof_kernel<<<dim3(nb), dim3(256), 0, stream>>>(
        h_g, r_g, W_g, b_g, dec_g, pi_g, (float*)d_out, nb);
}

// Round 13
// 50.509 us; speedup vs baseline: 1.0874x; 1.0874x over previous
//
#include <hip/hip_runtime.h>
#include <math.h>

// One 256-thread block per walker. S=2, N=8, D=256, I=4.
// r11 base (h staged once to LDS, register-W dot, butterfly reduce, NT stores)
// with: per-wave REDUNDANT dets (lanes 0-15 of every wave compute all 16 dets;
// anti broadcast via in-wave shfl) -> tail barrier + anti_s deleted, each wave
// stores as soon as its own det is done. launch_bounds(256,6): a[49] in regs.

typedef float f32x4 __attribute__((ext_vector_type(4)));

__global__ __launch_bounds__(256, 6)
void orbital_cof_kernel(const float* __restrict__ h_g,   // (B,16,256)
                        const float* __restrict__ r_g,   // (B,16,4,3)
                        const float* __restrict__ W_g,   // (2,256,8)
                        const float* __restrict__ b_g,   // (2,8)
                        const float* __restrict__ dec_g, // (2,4,8)
                        const float* __restrict__ pi_g,  // (2,4,8)
                        float* __restrict__ out,         // (2,B,8,256)
                        int nb)
{
    __shared__ float hs[16][256];    // 16 KB flat copy of this walker's h
    __shared__ float Ms[2][8][8];
    __shared__ float dist_s[64];     // [s*32 + n*4 + i]

    const int t = threadIdx.x;
    const int b = blockIdx.x;
    const int wave = t >> 6;         // 0..3
    const int lane = t & 63;
    const int s  = wave >> 1;        // spin
    const int kh = wave & 1;         // k half

    // ---- W into registers: lane covers d0=4*lane..+4, k=kh*4..+4 ----
    float wv[4][4];
    {
        const float* wp = W_g + s * 2048 + lane * 32 + kh * 4;
#pragma unroll
        for (int dd = 0; dd < 4; ++dd) {
            float4 w = *(const float4*)(wp + dd * 8);
            wv[dd][0] = w.x; wv[dd][1] = w.y; wv[dd][2] = w.z; wv[dd][3] = w.w;
        }
    }

    // ---- stage h: flat coalesced float4 copy ----
    const float4* h4p = (const float4*)(h_g + (size_t)b * 4096);
    float4* hs4 = (float4*)hs;
#pragma unroll
    for (int it = 0; it < 4; ++it)
        hs4[t + it * 256] = h4p[t + it * 256];

    // ---- distances (t<64): t = s*32 + n*4 + i matches r layout ----
    if (t < 64) {
        const float* rp = r_g + (size_t)b * 192 + t * 3;
        float x = rp[0], y = rp[1], z = rp[2];
        dist_s[t] = sqrtf(x * x + y * y + z * z);
    }
    __syncthreads();

    // ---- dot: p[n*4+kl] = sum over lane's 4 d of h[n][d]*W[d][k] ----
    float v[32];
#pragma unroll
    for (int n = 0; n < 8; ++n) {
        float4 hv = *(const float4*)&hs[s * 8 + n][lane * 4];
#pragma unroll
        for (int kl = 0; kl < 4; ++kl) {
            float acc;
            acc = hv.x * wv[0][kl];
            acc = fmaf(hv.y, wv[1][kl], acc);
            acc = fmaf(hv.z, wv[2][kl], acc);
            acc = fmaf(hv.w, wv[3][kl], acc);
            v[n * 4 + kl] = acc;
        }
    }

    // ---- halving-butterfly reduce over 64 lanes (lane 2m -> entry m) ----
#pragma unroll
    for (int i = 0; i < 16; ++i) {
        float send = (lane & 32) ? v[i] : v[i + 16];
        float recv = __shfl_xor(send, 32);
        v[i] = ((lane & 32) ? v[i + 16] : v[i]) + recv;
    }
#pragma unroll
    for (int i = 0; i < 8; ++i) {
        float send = (lane & 16) ? v[i] : v[i + 8];
        float recv = __shfl_xor(send, 16);
        v[i] = ((lane & 16) ? v[i + 8] : v[i]) + recv;
    }
#pragma unroll
    for (int i = 0; i < 4; ++i) {
        float send = (lane & 8) ? v[i] : v[i + 4];
        float recv = __shfl_xor(send, 8);
        v[i] = ((lane & 8) ? v[i + 4] : v[i]) + recv;
    }
#pragma unroll
    for (int i = 0; i < 2; ++i) {
        float send = (lane & 4) ? v[i] : v[i + 2];
        float recv = __shfl_xor(send, 4);
        v[i] = ((lane & 4) ? v[i + 2] : v[i]) + recv;
    }
    {
        float send = (lane & 2) ? v[0] : v[1];
        float recv = __shfl_xor(send, 2);
        v[0] = ((lane & 2) ? v[1] : v[0]) + recv;
    }
    float tot = v[0] + __shfl_xor(v[0], 1);

    // ---- env + bias -> Ms (even lanes hold (n,k) = lane>>1) ----
    if ((lane & 1) == 0) {
        int idx = lane >> 1;         // n*4 + kl
        int n = idx >> 2;
        int k = kh * 4 + (idx & 3);
        float lin = tot + b_g[s * 8 + k];
        float env = 0.f;
#pragma unroll
        for (int i = 0; i < 4; ++i) {
            float dd = dist_s[s * 32 + n * 4 + i];
            env = fmaf(pi_g[s * 32 + i * 8 + k], __expf(-dd * dec_g[s * 32 + i * 8 + k]), env);
        }
        Ms[s][n][k] = lin * env;
    }
    __syncthreads();

    // ---- per-wave redundant dets: lanes 0-15 of EVERY wave compute det
    //      (ss,n) = lane; same-address LDS reads across waves broadcast free ----
    float anti = 0.f;
    if (lane < 16) {
        int ss = lane >> 3;
        int n = lane & 7;
        float a[7][7];
#pragma unroll
        for (int i = 0; i < 7; ++i) {
            int src = i + (i >= n);  // skip row n
#pragma unroll
            for (int j = 0; j < 7; ++j) a[i][j] = Ms[ss][src][j + 1];  // skip col 0
        }
        float det = 1.f;
#pragma unroll
        for (int kk = 0; kk < 7; ++kk) {
#pragma unroll
            for (int i = kk + 1; i < 7; ++i) {
                bool sw = fabsf(a[i][kk]) > fabsf(a[kk][kk]);
#pragma unroll
                for (int j = kk; j < 7; ++j) {
                    float tk = a[kk][j], ti = a[i][j];
                    a[kk][j] = sw ? ti : tk;
                    a[i][j]  = sw ? tk : ti;
                }
                det = sw ? -det : det;
            }
            float piv = a[kk][kk];
            det *= piv;
            float rp = (piv != 0.f) ? (1.f / piv) : 0.f;
#pragma unroll
            for (int i = kk + 1; i < 7; ++i) {
                float f = a[i][kk] * rp;
#pragma unroll
                for (int j = kk + 1; j < 7; ++j) a[i][j] = fmaf(-f, a[kk][j], a[i][j]);
            }
        }
        float sgn = (n & 1) ? -1.f : 1.f;
        anti = Ms[ss][n][0] * sgn * det;
    }

    // ---- store: NO barrier — this wave's det done, anti broadcast in-wave.
    //      row = wave + it*4 (constant per wave-iteration), row<16 = det lane ----
#pragma unroll
    for (int it = 0; it < 4; ++it) {
        int row = wave + it * 4;     // s*8+n
        float aa = __shfl(anti, row);
        int d4 = lane << 2;
        float4 hv = *(const float4*)&hs[row][d4];
        f32x4 o;
        o.x = hv.x * aa; o.y = hv.y * aa; o.z = hv.z * aa; o.w = hv.w * aa;
        int so = row >> 3;
        int n = row & 7;
        size_t off = (size_t)so * (size_t)nb * 2048 + (size_t)b * 2048 + (size_t)(n * 256 + d4);
        __builtin_nontemporal_store(o, (f32x4*)(out + off));
    }
}

extern "C" void kernel_launch(void* const* d_in, const int* in_sizes, int n_in,
                              void* d_out, int out_size, void* d_ws, size_t ws_size,
                              hipStream_t stream) {
    int nb = in_sizes[0] / 4096;     // B = elems / (S*N*D)
    const float* h_g   = (const float*)d_in[0];
    const float* r_g   = (const float*)d_in[1];
    const float* W_g   = (const float*)d_in[2];
    const float* b_g   = (const float*)d_in[3];
    const float* dec_g = (const float*)d_in[4];
    const float* pi_g  = (const float*)d_in[5];
    orbital_cof_kernel<<<dim3(nb), dim3(256), 0, stream>>>(
        h_g, r_g, W_g, b_g, dec_g, pi_g, (float*)d_out, nb);
}

// Round 14
// 46.528 us; speedup vs baseline: 1.1804x; 1.0856x over previous
//
#include <hip/hip_runtime.h>
#include <math.h>

// One 256-thread block per WALKER (selected via XCD-chunk swizzle), S=2, N=8,
// D=256, I=4. r11 structure: h staged once to LDS (16KB), register-W dot,
// 64-lane halving butterfly, pivoted serial det (t<16), NT float4 stores.
// NEW vs r11: bijective XCD swizzle w = (bid%8)*(nb/8) + bid/8 so each XCD
// works a contiguous walker range (contiguous h reads + out writes per L2).

typedef float f32x4 __attribute__((ext_vector_type(4)));

__global__ __launch_bounds__(256, 8)
void orbital_cof_kernel(const float* __restrict__ h_g,   // (B,16,256)
                        const float* __restrict__ r_g,   // (B,16,4,3)
                        const float* __restrict__ W_g,   // (2,256,8)
                        const float* __restrict__ b_g,   // (2,8)
                        const float* __restrict__ dec_g, // (2,4,8)
                        const float* __restrict__ pi_g,  // (2,4,8)
                        float* __restrict__ out,         // (2,B,8,256)
                        int nb, int chunk)
{
    __shared__ float hs[16][256];    // 16 KB flat copy of this walker's h
    __shared__ float Ms[2][8][8];
    __shared__ float anti_s[16];
    __shared__ float dist_s[64];     // [s*32 + n*4 + i]

    const int t = threadIdx.x;
    // ---- XCD-chunk swizzle (bijective when nb % 8 == 0; fallback identity) ----
    int b;
    if (chunk > 0) {
        int bid = blockIdx.x;
        b = (bid & 7) * chunk + (bid >> 3);
    } else {
        b = blockIdx.x;
    }
    const int wave = t >> 6;         // 0..3
    const int lane = t & 63;
    const int s  = wave >> 1;        // spin
    const int kh = wave & 1;         // k half

    // ---- W into registers: lane covers d0=4*lane..+4, k=kh*4..+4 ----
    float wv[4][4];
    {
        const float* wp = W_g + s * 2048 + lane * 32 + kh * 4;
#pragma unroll
        for (int dd = 0; dd < 4; ++dd) {
            float4 w = *(const float4*)(wp + dd * 8);
            wv[dd][0] = w.x; wv[dd][1] = w.y; wv[dd][2] = w.z; wv[dd][3] = w.w;
        }
    }

    // ---- stage h: flat coalesced float4 copy ----
    const float4* h4p = (const float4*)(h_g + (size_t)b * 4096);
    float4* hs4 = (float4*)hs;
#pragma unroll
    for (int it = 0; it < 4; ++it)
        hs4[t + it * 256] = h4p[t + it * 256];

    // ---- distances (t<64): t = s*32 + n*4 + i matches r layout ----
    if (t < 64) {
        const float* rp = r_g + (size_t)b * 192 + t * 3;
        float x = rp[0], y = rp[1], z = rp[2];
        dist_s[t] = sqrtf(x * x + y * y + z * z);
    }
    __syncthreads();

    // ---- dot: p[n*4+kl] = sum over lane's 4 d of h[n][d]*W[d][k] ----
    float v[32];
#pragma unroll
    for (int n = 0; n < 8; ++n) {
        float4 hv = *(const float4*)&hs[s * 8 + n][lane * 4];
#pragma unroll
        for (int kl = 0; kl < 4; ++kl) {
            float acc;
            acc = hv.x * wv[0][kl];
            acc = fmaf(hv.y, wv[1][kl], acc);
            acc = fmaf(hv.z, wv[2][kl], acc);
            acc = fmaf(hv.w, wv[3][kl], acc);
            v[n * 4 + kl] = acc;
        }
    }

    // ---- halving-butterfly reduce over 64 lanes (lane 2m -> entry m) ----
#pragma unroll
    for (int i = 0; i < 16; ++i) {
        float send = (lane & 32) ? v[i] : v[i + 16];
        float recv = __shfl_xor(send, 32);
        v[i] = ((lane & 32) ? v[i + 16] : v[i]) + recv;
    }
#pragma unroll
    for (int i = 0; i < 8; ++i) {
        float send = (lane & 16) ? v[i] : v[i + 8];
        float recv = __shfl_xor(send, 16);
        v[i] = ((lane & 16) ? v[i + 8] : v[i]) + recv;
    }
#pragma unroll
    for (int i = 0; i < 4; ++i) {
        float send = (lane & 8) ? v[i] : v[i + 4];
        float recv = __shfl_xor(send, 8);
        v[i] = ((lane & 8) ? v[i + 4] : v[i]) + recv;
    }
#pragma unroll
    for (int i = 0; i < 2; ++i) {
        float send = (lane & 4) ? v[i] : v[i + 2];
        float recv = __shfl_xor(send, 4);
        v[i] = ((lane & 4) ? v[i + 2] : v[i]) + recv;
    }
    {
        float send = (lane & 2) ? v[0] : v[1];
        float recv = __shfl_xor(send, 2);
        v[0] = ((lane & 2) ? v[1] : v[0]) + recv;
    }
    float tot = v[0] + __shfl_xor(v[0], 1);

    // ---- env + bias -> Ms (even lanes hold (n,k) = lane>>1) ----
    if ((lane & 1) == 0) {
        int idx = lane >> 1;         // n*4 + kl
        int n = idx >> 2;
        int k = kh * 4 + (idx & 3);
        float lin = tot + b_g[s * 8 + k];
        float env = 0.f;
#pragma unroll
        for (int i = 0; i < 4; ++i) {
            float dd = dist_s[s * 32 + n * 4 + i];
            env = fmaf(pi_g[s * 32 + i * 8 + k], __expf(-dd * dec_g[s * 32 + i * 8 + k]), env);
        }
        Ms[s][n][k] = lin * env;
    }
    __syncthreads();

    // ---- 16 cofactor determinants (7x7, partial pivoting, reg-resident) ----
    if (t < 16) {
        int ss = t >> 3;
        int n = t & 7;
        float a[7][7];
#pragma unroll
        for (int i = 0; i < 7; ++i) {
            int src = i + (i >= n);  // skip row n
#pragma unroll
            for (int j = 0; j < 7; ++j) a[i][j] = Ms[ss][src][j + 1];  // skip col 0
        }
        float det = 1.f;
#pragma unroll
        for (int kk = 0; kk < 7; ++kk) {
#pragma unroll
            for (int i = kk + 1; i < 7; ++i) {
                bool sw = fabsf(a[i][kk]) > fabsf(a[kk][kk]);
#pragma unroll
                for (int j = kk; j < 7; ++j) {
                    float tk = a[kk][j], ti = a[i][j];
                    a[kk][j] = sw ? ti : tk;
                    a[i][j]  = sw ? tk : ti;
                }
                det = sw ? -det : det;
            }
            float piv = a[kk][kk];
            det *= piv;
            float rp = (piv != 0.f) ? (1.f / piv) : 0.f;
#pragma unroll
            for (int i = kk + 1; i < 7; ++i) {
                float f = a[i][kk] * rp;
#pragma unroll
                for (int j = kk + 1; j < 7; ++j) a[i][j] = fmaf(-f, a[kk][j], a[i][j]);
            }
        }
        float sgn = (n & 1) ? -1.f : 1.f;
        anti_s[t] = Ms[ss][n][0] * sgn * det;
    }
    __syncthreads();

    // ---- out = h * anti; coalesced NONTEMPORAL 16B stores ----
#pragma unroll
    for (int it = 0; it < 4; ++it) {
        int f4 = t + it * 256;
        int row = f4 >> 6;           // s*8+n
        int d4 = (f4 & 63) << 2;
        float4 hv = *(const float4*)&hs[row][d4];
        float aa = anti_s[row];
        f32x4 o;
        o.x = hv.x * aa; o.y = hv.y * aa; o.z = hv.z * aa; o.w = hv.w * aa;
        int so = row >> 3;
        int n = row & 7;
        size_t off = (size_t)so * (size_t)nb * 2048 + (size_t)b * 2048 + (size_t)(n * 256 + d4);
        __builtin_nontemporal_store(o, (f32x4*)(out + off));
    }
}

extern "C" void kernel_launch(void* const* d_in, const int* in_sizes, int n_in,
                              void* d_out, int out_size, void* d_ws, size_t ws_size,
                              hipStream_t stream) {
    int nb = in_sizes[0] / 4096;     // B = elems / (S*N*D)
    const float* h_g   = (const float*)d_in[0];
    const float* r_g   = (const float*)d_in[1];
    const float* W_g   = (const float*)d_in[2];
    const float* b_g   = (const float*)d_in[3];
    const float* dec_g = (const float*)d_in[4];
    const float* pi_g  = (const float*)d_in[5];
    int chunk = (nb % 8 == 0) ? (nb / 8) : 0;   // bijective only when divisible
    orbital_cof_kernel<<<dim3(nb), dim3(256), 0, stream>>>(
        h_g, r_g, W_g, b_g, dec_g, pi_g, (float*)d_out, nb, chunk);
}